// Round 7
// baseline (119.711 us; speedup 1.0000x reference)
//
#include <hip/hip_runtime.h>

#define NSEED 256
// floats per quarter-table: 32 pairs * 16 floats = 512, +8 skew so the four
// lane-classes' reads start at banks {0,8,16,24} -> disjoint 4-bank groups.
#define QSTRIDE 520

typedef float v2f __attribute__((ext_vector_type(2)));
typedef float v4f __attribute__((ext_vector_type(4)));

__device__ __forceinline__ float fast_exp(float x) {
  return __builtin_amdgcn_exp2f(x * 1.4426950408889634f);  // e^x via v_exp_f32
}
__device__ __forceinline__ float sigf(float x) {
  return 1.0f / (1.0f + fast_exp(-x));
}
__device__ __forceinline__ float med3(float x, float lo, float hi) {
  // == min(max(x,lo),hi) when lo<=hi (always true for our sorted slots)
  return __builtin_amdgcn_fmed3f(x, lo, hi);
}
__device__ __forceinline__ v2f vfma(v2f a, v2f b, v2f c) {
  return __builtin_elementwise_fma(a, b, c);  // -> v_pk_fma_f32
}

__global__ __launch_bounds__(256) void voronoi_kernel(
    const float* __restrict__ uv, const float* __restrict__ seeds,
    const float* __restrict__ w_raw, const float* __restrict__ h_raw,
    const float* __restrict__ theta, const float* __restrict__ a_raw,
    const float* __restrict__ seed_gates, float* __restrict__ out, int nq) {
  // Pair-transposed per-seed params, four bank-skewed quarter-tables.
  // Pair quads: {sx_a,sx_b,sy_a,sy_b} {a11,a11,a12,a12} {a21,a21,a22,a22}
  // {h_a,h_b,g_a,g_b}. +16 floats tail pad for the prefetch overread.
  __shared__ float Ppf[4 * QSTRIDE + 16];

  {
    int s = threadIdx.x;  // one thread per seed
    float sx = seeds[2 * s], sy = seeds[2 * s + 1];
    float th = theta[s];
    float c = cosf(th), sn = sinf(th);
    float sc = expf(a_raw[s]);
    float inv = 1.0f / sc;
    float h = 0.5f + 1.5f * sigf(h_raw[s]);
    float g = sigf(seed_gates[s]);
    int quarter = s >> 6, lp = (s >> 1) & 31, b = s & 1;
    float* base = Ppf + quarter * QSTRIDE + lp * 16;
    base[0 + b] = sx;
    base[2 + b] = sy;
    base[4 + b] = c * inv;
    base[6 + b] = sn * inv;
    base[8 + b] = -sn * sc;
    base[10 + b] = c * sc;
    base[12 + b] = h;
    base[14 + b] = g;
  }
  __syncthreads();

  // Four lanes per query: lane t&3 owns seed quarter [par*64, par*64+64).
  const int t = blockIdx.x * 256 + threadIdx.x;
  const int q = t >> 2;
  const int par = t & 3;
  if (q >= nq) return;
  const float2 uvq = ((const float2*)uv)[q];
  const v2f uu = {uvq.x, uvq.x}, vv = {uvq.y, uvq.y};
  const v2f eps2 = {1e-8f, 1e-8f};
  const float NK = -72.13475204444817f;  // -log2(e)/BETA, BETA=0.02

  float dk0 = 3e38f, dk1 = 3e38f, dk2 = 3e38f, dk3 = 3e38f;
  float dk4 = 3e38f, dk5 = 3e38f, dk6 = 3e38f, dk7 = 3e38f;
  int i0 = 0, i1 = 0;  // quarter-local; par<<6 OR'd in after the loop
  v2f S1 = {0.f, 0.f}, S2 = {0.f, 0.f}, Sh = {0.f, 0.f}, Sg = {0.f, 0.f};

  // Exact d^2 comparisons (strict <, old dk0/dk1) reproduce top_k's
  // lowest-index tie-break (round-4 lesson: no key masking).
#define INS(x, sidx)             \
  {                              \
    float _d = (x);              \
    bool c0 = _d < dk0;          \
    bool c1 = _d < dk1;          \
    int sh = c0 ? i0 : (sidx);   \
    i1 = c1 ? sh : i1;           \
    i0 = c0 ? (sidx) : i0;       \
    dk7 = med3(_d, dk6, dk7);    \
    dk6 = med3(_d, dk5, dk6);    \
    dk5 = med3(_d, dk4, dk5);    \
    dk4 = med3(_d, dk3, dk4);    \
    dk3 = med3(_d, dk2, dk3);    \
    dk2 = med3(_d, dk1, dk2);    \
    dk1 = med3(_d, dk0, dk1);    \
    dk0 = fminf(_d, dk0);        \
  }

  const v4f* __restrict__ PF = (const v4f*)(Ppf + par * QSTRIDE);
  // software pipeline: prefetch next pair's quads while computing current
  v4f q0 = PF[0], q1 = PF[1], q2 = PF[2], q3 = PF[3];
#pragma unroll 8
  for (int k = 0; k < 32; ++k) {
    v4f n0 = PF[4 * k + 4];
    v4f n1 = PF[4 * k + 5];
    v4f n2 = PF[4 * k + 6];
    v4f n3 = PF[4 * k + 7];
    v2f dx = uu - q0.xy, dy = vv - q0.zw;
    v2f xp = vfma(q1.xy, dx, q1.zw * dy);
    v2f yp = vfma(q2.xy, dx, q2.zw * dy);
    v2f d2 = vfma(xp, xp, vfma(yp, yp, eps2));
    INS(d2.x, 2 * k);  // compile-time sidx under unroll
    INS(d2.y, 2 * k + 1);
    // unshifted softmax terms 2^(-K*d): all consumers are scale-invariant
    float da = __builtin_amdgcn_sqrtf(d2.x);
    float db = __builtin_amdgcn_sqrtf(d2.y);
    v2f e;
    e.x = __builtin_amdgcn_exp2f(da * NK);
    e.y = __builtin_amdgcn_exp2f(db * NK);
    S1 += e;
    S2 = vfma(e, e, S2);
    Sh = vfma(e, q3.xy, Sh);
    Sg = vfma(e, q3.zw, Sg);
    q0 = n0; q1 = n1; q2 = n2; q3 = n3;
  }
#undef INS

  i0 |= par << 6;  // globalize seed indices
  i1 |= par << 6;

  // ---- two-stage cross-lane merge (xor 1, then xor 2) ----
  // Writer lane (par==0) always has "self" = lower seed range at both
  // stages, so strict-< with prefer-self matches top_k lowest-index ties.
#define CE(a, b)             \
  {                          \
    float _lo = fminf(a, b); \
    float _hi = fmaxf(a, b); \
    a = _lo;                 \
    b = _hi;                 \
  }
#define MERGE(W)                                                     \
  {                                                                  \
    float b0 = __shfl_xor(dk0, W), b1 = __shfl_xor(dk1, W);          \
    float b2 = __shfl_xor(dk2, W), b3 = __shfl_xor(dk3, W);          \
    float b4 = __shfl_xor(dk4, W), b5 = __shfl_xor(dk5, W);          \
    float b6 = __shfl_xor(dk6, W), b7 = __shfl_xor(dk7, W);          \
    int j0 = __shfl_xor(i0, W), j1 = __shfl_xor(i1, W);              \
    bool aw = b0 < dk0; /* partner strictly nearer */                \
    float ec1 = aw ? dk0 : dk1;                                      \
    int ic1 = aw ? i0 : i1;                                          \
    float ec2 = aw ? b1 : b0;                                        \
    int ic2 = aw ? j1 : j0;                                          \
    i0 = aw ? j0 : i0;                                               \
    i1 = (ec2 < ec1) ? ic2 : ic1;                                    \
    float m0 = fminf(dk0, b7), m1 = fminf(dk1, b6);                  \
    float m2 = fminf(dk2, b5), m3 = fminf(dk3, b4);                  \
    float m4 = fminf(dk4, b3), m5 = fminf(dk5, b2);                  \
    float m6 = fminf(dk6, b1), m7 = fminf(dk7, b0);                  \
    CE(m0, m4) CE(m1, m5) CE(m2, m6) CE(m3, m7)                      \
    CE(m0, m2) CE(m1, m3) CE(m4, m6) CE(m5, m7)                      \
    CE(m0, m1) CE(m2, m3) CE(m4, m5) CE(m6, m7)                      \
    dk0 = m0; dk1 = m1; dk2 = m2; dk3 = m3;                          \
    dk4 = m4; dk5 = m5; dk6 = m6; dk7 = m7;                          \
  }
  MERGE(1)
  MERGE(2)
#undef MERGE
#undef CE

  const int I0 = i0, I1 = i1;
  dk0 = __builtin_amdgcn_sqrtf(dk0);
  dk1 = __builtin_amdgcn_sqrtf(dk1);
  dk2 = __builtin_amdgcn_sqrtf(dk2);
  dk3 = __builtin_amdgcn_sqrtf(dk3);
  dk4 = __builtin_amdgcn_sqrtf(dk4);
  dk5 = __builtin_amdgcn_sqrtf(dk5);
  dk6 = __builtin_amdgcn_sqrtf(dk6);
  dk7 = __builtin_amdgcn_sqrtf(dk7);
  const float d1 = dk0, d3 = dk2;

  // combine softmax partials across the 4-lane group
  float S1s = S1.x + S1.y;
  float S2s = S2.x + S2.y;
  float Shs = Sh.x + Sh.y;
  float Sgs = Sg.x + Sg.y;
  S1s += __shfl_xor(S1s, 1);
  S2s += __shfl_xor(S2s, 1);
  Shs += __shfl_xor(Shs, 1);
  Sgs += __shfl_xor(Sgs, 1);
  S1s += __shfl_xor(S1s, 2);
  S2s += __shfl_xor(S2s, 2);
  Shs += __shfl_xor(Shs, 2);
  Sgs += __shfl_xor(Sgs, 2);

  // ---- Epilogue ----
  float ax = seeds[2 * I0], ay = seeds[2 * I0 + 1];
  float bx = seeds[2 * I1], by = seeds[2 * I1 + 1];
  float pdx = ax - bx, pdy = ay - by;
  float pd = __builtin_amdgcn_sqrtf(fmaf(pdx, pdx, pdy * pdy));
  float wmax = fmaxf(0.8f * pd, 0.005f + 1e-8f);
  float wr01 = w_raw[(I0 << 8) + I1];
  float wr10 = w_raw[(I1 << 8) + I0];
  float w_pair = 0.005f + (wmax - 0.005f) * 0.5f * (sigf(wr01 * 0.2f) + sigf(wr10 * 0.2f));

  // k_eff = 1/(sum p^2 + EPS) = S1^2/(S2 + EPS*S1^2)  (shift-invariant)
  float s1sq = S1s * S1s;
  float keff = s1sq / fmaf(1e-8f, s1sq, S2s);
  float bonus = 0.15f * sigf((keff - 3.0f) * (1.0f / 0.35f));

  float tt = (d3 - d1) / (w_pair + 1e-8f);
  float t15 = tt * __builtin_amdgcn_sqrtf(tt);
  float triple = 0.15f * fast_exp(-t15);

  float w_eff = w_pair * (1.0f + bonus + triple);

  const float HT = 360.6737602222409f;  // 0.5/tau * log2(e), tau=0.002
  float acc = 1.0f;
  acc += __builtin_amdgcn_exp2f((dk1 - dk2) * HT);
  acc += __builtin_amdgcn_exp2f((dk1 - dk3) * HT);
  acc += __builtin_amdgcn_exp2f((dk1 - dk4) * HT);
  acc += __builtin_amdgcn_exp2f((dk1 - dk5) * HT);
  acc += __builtin_amdgcn_exp2f((dk1 - dk6) * HT);
  acc += __builtin_amdgcn_exp2f((dk1 - dk7) * HT);
  float b1s = 0.5f * (dk1 - d1);
  float sdist = b1s - 0.002f * 0.6931471805599453f * __builtin_amdgcn_logf(acc);

  float wall = sigf((0.5f * w_eff - sdist) * 50.0f);
  float invS1 = 1.0f / S1s;
  if (par == 0) out[q] = wall * (Sgs * invS1) * (Shs * invS1);
}

extern "C" void kernel_launch(void* const* d_in, const int* in_sizes, int n_in,
                              void* d_out, int out_size, void* d_ws, size_t ws_size,
                              hipStream_t stream) {
  (void)in_sizes;
  (void)n_in;
  (void)d_ws;
  (void)ws_size;
  const float* uv = (const float*)d_in[0];
  const float* seeds = (const float*)d_in[1];
  const float* w_raw = (const float*)d_in[2];
  const float* h_raw = (const float*)d_in[3];
  const float* theta = (const float*)d_in[4];
  const float* a_raw = (const float*)d_in[5];
  const float* gates = (const float*)d_in[6];
  float* out = (float*)d_out;

  int nq = out_size;
  long long threads = 4LL * nq;  // 4 lanes per query
  int grid = (int)((threads + 255) / 256);
  voronoi_kernel<<<grid, 256, 0, stream>>>(uv, seeds, w_raw, h_raw, theta,
                                           a_raw, gates, out, nq);
}

// Round 8
// 114.638 us; speedup vs baseline: 1.0443x; 1.0443x over previous
//
#include <hip/hip_runtime.h>

#define NSEED 256

typedef float v2f __attribute__((ext_vector_type(2)));
typedef float v4f __attribute__((ext_vector_type(4)));

__device__ __forceinline__ float fast_exp(float x) {
  return __builtin_amdgcn_exp2f(x * 1.4426950408889634f);  // e^x via v_exp_f32
}
__device__ __forceinline__ float sigf(float x) {
  return 1.0f / (1.0f + fast_exp(-x));
}
__device__ __forceinline__ float med3(float x, float lo, float hi) {
  // == min(max(x,lo),hi) when lo<=hi (always true for our sorted slots)
  return __builtin_amdgcn_fmed3f(x, lo, hi);
}
__device__ __forceinline__ v2f vfma(v2f a, v2f b, v2f c) {
  return __builtin_elementwise_fma(a, b, c);  // -> v_pk_fma_f32
}

// One-time setup: pair-transposed param table in global ws.
// Per seed-pair p (seeds 2p, 2p+1), 16 floats:
//  {sx_a,sx_b, sy_a,sy_b, a11_a,a11_b, a12_a,a12_b,
//   a21_a,a21_b, a22_a,a22_b, h_a,h_b, g_a,g_b}
__global__ void seed_setup_kernel(const float* __restrict__ seeds,
                                  const float* __restrict__ h_raw,
                                  const float* __restrict__ theta,
                                  const float* __restrict__ a_raw,
                                  const float* __restrict__ seed_gates,
                                  float* __restrict__ Pg) {
  int s = threadIdx.x;
  if (s >= NSEED) return;
  float sx = seeds[2 * s], sy = seeds[2 * s + 1];
  float th = theta[s];
  float c = cosf(th), sn = sinf(th);
  float sc = expf(a_raw[s]);
  float inv = 1.0f / sc;
  float h = 0.5f + 1.5f * sigf(h_raw[s]);  // H_MIN + (H_MAX-H_MIN)*sigmoid
  float g = sigf(seed_gates[s]);
  float* base = Pg + (s >> 1) * 16;
  int b = s & 1;
  base[0 + b] = sx;
  base[2 + b] = sy;
  base[4 + b] = c * inv;
  base[6 + b] = sn * inv;
  base[8 + b] = -sn * sc;
  base[10 + b] = c * sc;
  base[12 + b] = h;
  base[14 + b] = g;
}

__global__ __launch_bounds__(256) void voronoi_kernel(
    const float* __restrict__ uv, const float* __restrict__ seeds,
    const float* __restrict__ w_raw, const float* __restrict__ Pg,
    float* __restrict__ out, int nq) {
  const int q = blockIdx.x * 256 + threadIdx.x;
  if (q >= nq) return;
  const float2 uvq = ((const float2*)uv)[q];
  const v2f uu = {uvq.x, uvq.x}, vv = {uvq.y, uvq.y};
  const v2f eps2 = {1e-8f, 1e-8f};
  const float NK = -72.13475204444817f;  // -log2(e)/BETA, BETA=0.02

  float dk0 = 3e38f, dk1 = 3e38f, dk2 = 3e38f, dk3 = 3e38f;
  float dk4 = 3e38f, dk5 = 3e38f, dk6 = 3e38f, dk7 = 3e38f;
  int i0 = 0, i1 = 0;
  v2f S1 = {0.f, 0.f}, S2 = {0.f, 0.f}, Sh = {0.f, 0.f}, Sg = {0.f, 0.f};

  // Exact d^2 comparisons (strict <, old dk0/dk1) reproduce top_k's
  // lowest-index tie-break (round-4 lesson: no key masking).
#define INS(x, sidx)             \
  {                              \
    float _d = (x);              \
    bool c0 = _d < dk0;          \
    bool c1 = _d < dk1;          \
    int sh = c0 ? i0 : (sidx);   \
    i1 = c1 ? sh : i1;           \
    i0 = c0 ? (sidx) : i0;       \
    dk7 = med3(_d, dk6, dk7);    \
    dk6 = med3(_d, dk5, dk6);    \
    dk5 = med3(_d, dk4, dk5);    \
    dk4 = med3(_d, dk3, dk4);    \
    dk3 = med3(_d, dk2, dk3);    \
    dk2 = med3(_d, dk1, dk2);    \
    dk1 = med3(_d, dk0, dk1);    \
    dk0 = fminf(_d, dk0);        \
  }

  // Wave-uniform param address -> scalar s_load (no VALU, no LDS).
  const v4f* __restrict__ PG = (const v4f*)Pg;
#pragma unroll 8
  for (int k = 0; k < NSEED / 2; ++k) {
    v4f q0 = PG[4 * k + 0];
    v4f q1 = PG[4 * k + 1];
    v4f q2 = PG[4 * k + 2];
    v4f q3 = PG[4 * k + 3];
    v2f dx = uu - q0.xy, dy = vv - q0.zw;
    v2f xp = vfma(q1.xy, dx, q1.zw * dy);
    v2f yp = vfma(q2.xy, dx, q2.zw * dy);
    v2f d2 = vfma(xp, xp, vfma(yp, yp, eps2));
    INS(d2.x, 2 * k);
    INS(d2.y, 2 * k + 1);
    // unshifted softmax terms 2^(-K*d): all consumers are scale-invariant
    float da = __builtin_amdgcn_sqrtf(d2.x);
    float db = __builtin_amdgcn_sqrtf(d2.y);
    v2f e;
    e.x = __builtin_amdgcn_exp2f(da * NK);
    e.y = __builtin_amdgcn_exp2f(db * NK);
    S1 += e;
    S2 = vfma(e, e, S2);
    Sh = vfma(e, q3.xy, Sh);
    Sg = vfma(e, q3.zw, Sg);
  }
#undef INS

  dk0 = __builtin_amdgcn_sqrtf(dk0);
  dk1 = __builtin_amdgcn_sqrtf(dk1);
  dk2 = __builtin_amdgcn_sqrtf(dk2);
  dk3 = __builtin_amdgcn_sqrtf(dk3);
  dk4 = __builtin_amdgcn_sqrtf(dk4);
  dk5 = __builtin_amdgcn_sqrtf(dk5);
  dk6 = __builtin_amdgcn_sqrtf(dk6);
  dk7 = __builtin_amdgcn_sqrtf(dk7);
  const float d1 = dk0, d3 = dk2;

  float S1s = S1.x + S1.y;
  float S2s = S2.x + S2.y;
  float Shs = Sh.x + Sh.y;
  float Sgs = Sg.x + Sg.y;

  // ---- Epilogue ----
  float ax = seeds[2 * i0], ay = seeds[2 * i0 + 1];
  float bx = seeds[2 * i1], by = seeds[2 * i1 + 1];
  float pdx = ax - bx, pdy = ay - by;
  float pd = __builtin_amdgcn_sqrtf(fmaf(pdx, pdx, pdy * pdy));
  float wmax = fmaxf(0.8f * pd, 0.005f + 1e-8f);
  float wr01 = w_raw[(i0 << 8) + i1];
  float wr10 = w_raw[(i1 << 8) + i0];
  float w_pair = 0.005f + (wmax - 0.005f) * 0.5f * (sigf(wr01 * 0.2f) + sigf(wr10 * 0.2f));

  // k_eff = 1/(sum p^2 + EPS) = S1^2/(S2 + EPS*S1^2)  (shift-invariant)
  float s1sq = S1s * S1s;
  float keff = s1sq / fmaf(1e-8f, s1sq, S2s);
  float bonus = 0.15f * sigf((keff - 3.0f) * (1.0f / 0.35f));

  float tt = (d3 - d1) / (w_pair + 1e-8f);
  float t15 = tt * __builtin_amdgcn_sqrtf(tt);
  float triple = 0.15f * fast_exp(-t15);

  float w_eff = w_pair * (1.0f + bonus + triple);

  const float HT = 360.6737602222409f;  // 0.5/tau * log2(e), tau=0.002
  float acc = 1.0f;
  acc += __builtin_amdgcn_exp2f((dk1 - dk2) * HT);
  acc += __builtin_amdgcn_exp2f((dk1 - dk3) * HT);
  acc += __builtin_amdgcn_exp2f((dk1 - dk4) * HT);
  acc += __builtin_amdgcn_exp2f((dk1 - dk5) * HT);
  acc += __builtin_amdgcn_exp2f((dk1 - dk6) * HT);
  acc += __builtin_amdgcn_exp2f((dk1 - dk7) * HT);
  float b1s = 0.5f * (dk1 - d1);
  float sdist = b1s - 0.002f * 0.6931471805599453f * __builtin_amdgcn_logf(acc);

  float wall = sigf((0.5f * w_eff - sdist) * 50.0f);
  float invS1 = 1.0f / S1s;
  out[q] = wall * (Sgs * invS1) * (Shs * invS1);
}

extern "C" void kernel_launch(void* const* d_in, const int* in_sizes, int n_in,
                              void* d_out, int out_size, void* d_ws, size_t ws_size,
                              hipStream_t stream) {
  (void)in_sizes;
  (void)n_in;
  (void)ws_size;
  const float* uv = (const float*)d_in[0];
  const float* seeds = (const float*)d_in[1];
  const float* w_raw = (const float*)d_in[2];
  const float* h_raw = (const float*)d_in[3];
  const float* theta = (const float*)d_in[4];
  const float* a_raw = (const float*)d_in[5];
  const float* gates = (const float*)d_in[6];
  float* out = (float*)d_out;
  float* Pg = (float*)d_ws;  // 128 pairs * 16 floats = 8 KB

  seed_setup_kernel<<<1, 256, 0, stream>>>(seeds, h_raw, theta, a_raw, gates, Pg);
  int nq = out_size;
  int grid = (nq + 255) / 256;
  voronoi_kernel<<<grid, 256, 0, stream>>>(uv, seeds, w_raw, Pg, out, nq);
}